// Round 1
// baseline (510.798 us; speedup 1.0000x reference)
//
#include <hip/hip_runtime.h>
#include <hip/hip_bf16.h>

#define C 128            // C_IN == C_OUT == 128
#define TPB 256

// ---------------- workspace layout (bytes) ----------------
#define OFF_FLAG 0x0
#define OFF_DEGD 0x400       // int[N]   in-degree (by dst)
#define OFF_CNTS 0x80000     // int[N]   out-degree (by src)
#define OFF_INVD 0x100000    // float[N] 1/(degD+1)
#define OFF_OFFS 0x180000    // int[N]   CSR row offsets (exclusive scan of cntS)
#define OFF_CUR  0x200000    // int[N]   fill cursors
#define OFF_BSUM 0x280000    // int[512] scan partials
#define OFF_EDST 0x300000    // int[E]   CSR adjacency (dst per slot)
#define OFF_HN   0xA00000    // float[N*128] hn = (x@W^T) * invd

// Detect whether edge_index is int64 (high 32-bit words all zero) or int32.
__global__ void detect_kernel(const unsigned int* __restrict__ ew, int nCheck,
                              int* __restrict__ flagp) {
    __shared__ int s;
    if (threadIdx.x == 0) s = 0;
    __syncthreads();
    int any = 0;
    for (int i = threadIdx.x; i < nCheck; i += TPB)
        any |= (ew[2 * i + 1] != 0u);
    if (any) s = 1;              // some high word nonzero -> int32 layout
    __syncthreads();
    if (threadIdx.x == 0) *flagp = s;
}

__device__ __forceinline__ void load_edge(const void* edges, long long E, int is32,
                                          long long e, int& s, int& d) {
    if (is32) {
        const int* p = (const int*)edges;
        s = p[e]; d = p[E + e];
    } else {
        const long long* p = (const long long*)edges;
        s = (int)p[e]; d = (int)p[E + e];
    }
}

__global__ void zero3_kernel(int* degD, int* cntS, int* cur, int N) {
    int i = blockIdx.x * TPB + threadIdx.x;
    if (i < N) { degD[i] = 0; cntS[i] = 0; cur[i] = 0; }
}

__global__ void count_kernel(const void* __restrict__ edges, const int* __restrict__ flagp,
                             long long E, int* __restrict__ degD, int* __restrict__ cntS) {
    long long e = (long long)blockIdx.x * TPB + threadIdx.x;
    if (e >= E) return;
    int s, d;
    load_edge(edges, E, *flagp, e, s, d);
    atomicAdd(&degD[d], 1);
    atomicAdd(&cntS[s], 1);
}

__global__ void invd_kernel(const int* __restrict__ degD, float* __restrict__ invd, int N) {
    int i = blockIdx.x * TPB + threadIdx.x;
    if (i < N) invd[i] = 1.0f / (float)(degD[i] + 1);
}

// exclusive scan of cntS -> offS ; per-block totals -> bsum
__global__ __launch_bounds__(TPB) void scan1_kernel(const int* __restrict__ cntS,
                                                    int* __restrict__ offS,
                                                    int* __restrict__ bsum, int N) {
    __shared__ int s[TPB];
    const int t = threadIdx.x;
    const int i = blockIdx.x * TPB + t;
    int v = (i < N) ? cntS[i] : 0;
    s[t] = v;
    __syncthreads();
    for (int d = 1; d < TPB; d <<= 1) {
        int add = (t >= d) ? s[t - d] : 0;
        __syncthreads();
        s[t] += add;
        __syncthreads();
    }
    if (i < N) offS[i] = s[t] - v;                 // local exclusive
    if (t == TPB - 1) bsum[blockIdx.x] = s[t];     // block total
}

__global__ void scan2_kernel(int* __restrict__ bsum, int nb) {
    __shared__ int s[512];
    const int t = threadIdx.x;   // 512 threads
    int v = (t < nb) ? bsum[t] : 0;
    s[t] = v;
    __syncthreads();
    for (int d = 1; d < 512; d <<= 1) {
        int add = (t >= d) ? s[t - d] : 0;
        __syncthreads();
        s[t] += add;
        __syncthreads();
    }
    if (t < nb) bsum[t] = s[t] - v;                // exclusive
}

__global__ void scan3_kernel(int* __restrict__ offS, const int* __restrict__ bsum, int N) {
    int i = blockIdx.x * TPB + threadIdx.x;
    if (i < N) offS[i] += bsum[blockIdx.x];
}

__global__ void fill_kernel(const void* __restrict__ edges, const int* __restrict__ flagp,
                            long long E, const int* __restrict__ offS,
                            int* __restrict__ cur, int* __restrict__ eDst) {
    long long e = (long long)blockIdx.x * TPB + threadIdx.x;
    if (e >= E) return;
    int s, d;
    load_edge(edges, E, *flagp, e, s, d);
    int pos = atomicAdd(&cur[s], 1);
    eDst[offS[s] + pos] = d;
}

// hn[i][:] = (x[i] @ W^T) * invd[i] ; W staged in LDS, broadcast reads per wave.
__global__ __launch_bounds__(TPB) void gemm_hn_kernel(const float* __restrict__ x,
                                                      const float* __restrict__ W,
                                                      const float* __restrict__ invd,
                                                      float* __restrict__ hn, int N) {
    __shared__ float Ws[C * C];          // 64 KB, W[o][k]
    __shared__ float xs[64][C + 4];      // 33 KB, pad to avoid bank conflicts
    const int t = threadIdx.x;
    const int base = blockIdx.x * 64;

    for (int i = t; i < C * C / 4; i += TPB)
        ((float4*)Ws)[i] = ((const float4*)W)[i];
    for (int i = t; i < 64 * 32; i += TPB) {
        int r = i >> 5, k4 = i & 31;
        int gr = base + r;
        float4 v = make_float4(0.f, 0.f, 0.f, 0.f);
        if (gr < N) v = ((const float4*)(x + (size_t)gr * C))[k4];
        *(float4*)&xs[r][k4 * 4] = v;
    }
    __syncthreads();

    const int row = t & 63;        // 64 rows per block
    const int cg  = t >> 6;        // 4 col groups of 32 (wave-uniform -> LDS broadcast)
    float acc[32];
#pragma unroll
    for (int o = 0; o < 32; ++o) acc[o] = 0.f;

    for (int k4 = 0; k4 < 32; ++k4) {
        const float4 xv = *(const float4*)&xs[row][k4 * 4];
#pragma unroll
        for (int o = 0; o < 32; ++o) {
            const float4 wv = *(const float4*)&Ws[(cg * 32 + o) * C + k4 * 4];
            acc[o] += xv.x * wv.x + xv.y * wv.y + xv.z * wv.z + xv.w * wv.w;
        }
    }

    const int gr = base + row;
    if (gr < N) {
        const float idv = invd[gr];
        float* hp = hn + (size_t)gr * C + cg * 32;
#pragma unroll
        for (int o4 = 0; o4 < 8; ++o4) {
            float4 v;
            v.x = acc[o4 * 4 + 0] * idv;
            v.y = acc[o4 * 4 + 1] * idv;
            v.z = acc[o4 * 4 + 2] * idv;
            v.w = acc[o4 * 4 + 3] * idv;
            ((float4*)hp)[o4] = v;
        }
    }
}

// One wave per node: out[i] = (sum_{j in adj[i]} hn[j] + hn[i]) * invd[i]
__global__ __launch_bounds__(TPB) void gather_kernel(const int* __restrict__ offS,
                                                     const int* __restrict__ cntS,
                                                     const int* __restrict__ eDst,
                                                     const float* __restrict__ hn,
                                                     const float* __restrict__ invd,
                                                     float* __restrict__ out, int N) {
    const int lane = threadIdx.x & 63;
    const int w = (blockIdx.x * TPB + threadIdx.x) >> 6;
    if (w >= N) return;
    const int beg = offS[w];
    const int cnt = cntS[w];
    float2 acc = *(const float2*)(hn + (size_t)w * C + lane * 2);   // self loop
    int j = 0;
#pragma unroll 1
    for (; j + 4 <= cnt; j += 4) {
        const int d0 = eDst[beg + j + 0];
        const int d1 = eDst[beg + j + 1];
        const int d2 = eDst[beg + j + 2];
        const int d3 = eDst[beg + j + 3];
        const float2 v0 = *(const float2*)(hn + (size_t)d0 * C + lane * 2);
        const float2 v1 = *(const float2*)(hn + (size_t)d1 * C + lane * 2);
        const float2 v2 = *(const float2*)(hn + (size_t)d2 * C + lane * 2);
        const float2 v3 = *(const float2*)(hn + (size_t)d3 * C + lane * 2);
        acc.x += v0.x + v1.x + v2.x + v3.x;
        acc.y += v0.y + v1.y + v2.y + v3.y;
    }
    for (; j < cnt; ++j) {
        const int d = eDst[beg + j];
        const float2 v = *(const float2*)(hn + (size_t)d * C + lane * 2);
        acc.x += v.x; acc.y += v.y;
    }
    const float s = invd[w];
    *(float2*)(out + (size_t)w * C + lane * 2) = make_float2(acc.x * s, acc.y * s);
}

extern "C" void kernel_launch(void* const* d_in, const int* in_sizes, int n_in,
                              void* d_out, int out_size, void* d_ws, size_t ws_size,
                              hipStream_t stream) {
    const float* x = (const float*)d_in[0];
    const void* edges = d_in[1];
    const float* W = (const float*)d_in[2];
    float* out = (float*)d_out;

    const int N = in_sizes[0] / C;
    const long long E = (long long)in_sizes[1] / 2;

    char* ws = (char*)d_ws;
    int*   flagp = (int*)(ws + OFF_FLAG);
    int*   degD  = (int*)(ws + OFF_DEGD);
    int*   cntS  = (int*)(ws + OFF_CNTS);
    float* invd  = (float*)(ws + OFF_INVD);
    int*   offS  = (int*)(ws + OFF_OFFS);
    int*   cur   = (int*)(ws + OFF_CUR);
    int*   bsum  = (int*)(ws + OFF_BSUM);
    int*   eDst  = (int*)(ws + OFF_EDST);
    float* hn    = (float*)(ws + OFF_HN);

    const int nBlkN = (N + TPB - 1) / TPB;                  // 391
    const int nBlkE = (int)((E + TPB - 1) / TPB);           // 6250

    int nCheck = (int)(E < 4096 ? E : 4096);
    detect_kernel<<<1, TPB, 0, stream>>>((const unsigned int*)edges, nCheck, flagp);
    zero3_kernel<<<nBlkN, TPB, 0, stream>>>(degD, cntS, cur, N);
    count_kernel<<<nBlkE, TPB, 0, stream>>>(edges, flagp, E, degD, cntS);
    invd_kernel<<<nBlkN, TPB, 0, stream>>>(degD, invd, N);
    scan1_kernel<<<nBlkN, TPB, 0, stream>>>(cntS, offS, bsum, N);
    scan2_kernel<<<1, 512, 0, stream>>>(bsum, nBlkN);
    scan3_kernel<<<nBlkN, TPB, 0, stream>>>(offS, bsum, N);
    fill_kernel<<<nBlkE, TPB, 0, stream>>>(edges, flagp, E, offS, cur, eDst);

    const int nBlkG = (N + 63) / 64;                        // 1563
    gemm_hn_kernel<<<nBlkG, TPB, 0, stream>>>(x, W, invd, hn, N);

    const int nBlkA = (N * 64 + TPB - 1) / TPB;             // 25000 (wave per node)
    gather_kernel<<<nBlkA, TPB, 0, stream>>>(offS, cntS, eDst, hn, invd, out, N);
}